// Round 12
// baseline (386.945 us; speedup 1.0000x reference)
//
#include <hip/hip_runtime.h>
#include <hip/hip_bf16.h>

// ResidualGATBlock: LN1 -> GATv2(4 heads) -> gelu -> +time_cond +x -> LN2 -> FFN -> residual
// N=100000, E=1600000, D=128, H=4, HD=32, B=8, TD=128. f32 I/O.
// Round 12: (1) per-head fs/fdB layout [H][N][32] + head-major gather
// (working set 6.4MB/phase -> XCD-L2 resident; was 84% L2 miss on 25.6MB);
// (2) ln1/fill block roles interleaved by parity (real on-CU overlap).

#define RB 16
#define NEG_SLOPE 0.2f
#define LN_EPS 1e-5f

typedef __attribute__((ext_vector_type(8))) short short8v;   // 8 bf16 (4 VGPRs)
typedef __attribute__((ext_vector_type(4))) float floatx4;   // MFMA accum
typedef __attribute__((ext_vector_type(2))) float f32x2;     // packed f32 (VOP3P)

__device__ __forceinline__ float gelu_erf(float v) {
    return 0.5f * v * (1.0f + erff(v * 0.70710678118654752f));
}
__device__ __forceinline__ unsigned short f2bf(float f) {    // RNE f32->bf16
    unsigned int u = __float_as_uint(f);
    u += 0x7fffu + ((u >> 16) & 1u);
    return (unsigned short)(u >> 16);
}

// ---------------------------------------------------------------------------
// pack W [K][C] f32 row-major -> bf16 B-fragments for mfma_f32_16x16x32_bf16.
// ---------------------------------------------------------------------------
__device__ __forceinline__ void pack_region(
    const float* __restrict__ W, unsigned short* __restrict__ P, int K, int C, int idx)
{
    int total = (K >> 5) * (C >> 4) * 64;
    if (idx >= total) return;
    int lane = idx & 63;
    int f = idx >> 6;
    int nkt = K >> 5;
    int nt = f / nkt, kt = f - nt * nkt;
    int col = nt * 16 + (lane & 15);
    int k0 = kt * 32 + 8 * (lane >> 4);
    short8v v;
    #pragma unroll
    for (int i = 0; i < 8; ++i)
        v[i] = (short)f2bf(W[(size_t)(k0 + i) * C + col]);
    *(short8v*)(P + (size_t)idx * 8) = v;
}

// ---------------------------------------------------------------------------
// prep: blocks [0,nRank) = csr_rank; then 1 time_mlp + 48 pack blocks.
// deg pre-zeroed by memsetAsync.
// ---------------------------------------------------------------------------
__global__ __launch_bounds__(256) void prep(
    const int* __restrict__ dst, int* __restrict__ deg, int* __restrict__ rank,
    int E, int nRank,
    const float* __restrict__ temb, const float* __restrict__ tW,
    const float* __restrict__ tb, float* __restrict__ tc, int B,
    const float* __restrict__ Wsrc, unsigned short* __restrict__ pWs,
    const float* __restrict__ Wdst, unsigned short* __restrict__ pWd,
    const float* __restrict__ W1,   unsigned short* __restrict__ pW1,
    const float* __restrict__ W2,   unsigned short* __restrict__ pW2)
{
    const int t = threadIdx.x;
    if (blockIdx.x < nRank) {
        int e = blockIdx.x * 256 + t;
        if (e < E) rank[e] = atomicAdd(&deg[dst[e]], 1);
        return;
    }
    const int bid = blockIdx.x - nRank;
    if (bid == 0) {
        __shared__ float te[8 * 128];
        for (int i = t; i < B * 128; i += 256) te[i] = temb[i];
        __syncthreads();
        int c = t & 127, half = t >> 7;
        for (int b = half * 4; b < half * 4 + 4; ++b) {
            if (b >= B) break;
            float acc = 0.f;
            for (int k = 0; k < 128; ++k) acc = fmaf(te[b * 128 + k], tW[k * 128 + c], acc);
            tc[b * 128 + c] = gelu_erf(acc + tb[c]);
        }
    } else if (bid < 9) {
        pack_region(Wsrc, pWs, 128, 128, (bid - 1) * 256 + t);
    } else if (bid < 17) {
        pack_region(Wdst, pWd, 128, 128, (bid - 9) * 256 + t);
    } else if (bid < 33) {
        pack_region(W1, pW1, 128, 256, (bid - 17) * 256 + t);
    } else {
        pack_region(W2, pW2, 256, 128, (bid - 33) * 256 + t);
    }
}

// ---------------------------------------------------------------------------
// Parallel scan (3 phases)
// ---------------------------------------------------------------------------
__global__ __launch_bounds__(256) void scan_blocks(
    const int* __restrict__ deg, int* __restrict__ rs, int* __restrict__ btot, int N)
{
    __shared__ int wtot[4];
    const int t    = threadIdx.x;
    const int idx  = blockIdx.x * 1024 + t * 4;
    int d0 = 0, d1 = 0, d2 = 0, d3 = 0;
    if (idx + 3 < N) {
        int4 v = *(const int4*)(deg + idx);
        d0 = v.x; d1 = v.y; d2 = v.z; d3 = v.w;
    } else {
        if (idx     < N) d0 = deg[idx];
        if (idx + 1 < N) d1 = deg[idx + 1];
        if (idx + 2 < N) d2 = deg[idx + 2];
        if (idx + 3 < N) d3 = deg[idx + 3];
    }
    const int ts = d0 + d1 + d2 + d3;
    const int lane = t & 63, w = t >> 6;
    int incl = ts;
    #pragma unroll
    for (int m = 1; m < 64; m <<= 1) { int u = __shfl_up(incl, m); if (lane >= m) incl += u; }
    if (lane == 63) wtot[w] = incl;
    __syncthreads();
    int woff = 0;
    #pragma unroll
    for (int i = 0; i < 4; ++i) woff += (i < w) ? wtot[i] : 0;
    const int p = woff + incl - ts;
    if (idx + 3 < N) {
        int4 o;
        o.x = p; o.y = p + d0; o.z = p + d0 + d1; o.w = p + d0 + d1 + d2;
        *(int4*)(rs + idx) = o;
    } else {
        if (idx     < N) rs[idx]     = p;
        if (idx + 1 < N) rs[idx + 1] = p + d0;
        if (idx + 2 < N) rs[idx + 2] = p + d0 + d1;
        if (idx + 3 < N) rs[idx + 3] = p + d0 + d1 + d2;
    }
    if (t == 255) btot[blockIdx.x] = woff + incl;
}

__global__ __launch_bounds__(64) void scan_tops(
    int* __restrict__ btot, int nb, int* __restrict__ rs, int N, int E)
{
    const int lane = threadIdx.x;
    int a0 = (2 * lane     < nb) ? btot[2 * lane]     : 0;
    int a1 = (2 * lane + 1 < nb) ? btot[2 * lane + 1] : 0;
    const int ts = a0 + a1;
    int incl = ts;
    #pragma unroll
    for (int m = 1; m < 64; m <<= 1) { int u = __shfl_up(incl, m); if (lane >= m) incl += u; }
    const int ex = incl - ts;
    if (2 * lane     < nb) btot[2 * lane]     = ex;
    if (2 * lane + 1 < nb) btot[2 * lane + 1] = ex + a0;
    if (lane == 0) rs[N] = E;
}

__global__ __launch_bounds__(256) void scan_add(
    int* __restrict__ rs, const int* __restrict__ btot, int N)
{
    int i = blockIdx.x * 256 + threadIdx.x;
    if (i < N) rs[i] += btot[i >> 10];
}

// ---------------------------------------------------------------------------
// Fused ln1 + fill, roles INTERLEAVED by block parity so latency-bound
// scatter blocks and compute-bound GEMM blocks co-reside on each CU.
// fs/fdB written in per-head layout [H][N][32] bf16.
// ---------------------------------------------------------------------------
__global__ __launch_bounds__(256) void ln1_fill(
    const float* __restrict__ x,
    const float* __restrict__ ln_g, const float* __restrict__ ln_b,
    const unsigned short* __restrict__ pWs, const float* __restrict__ bsrc,
    const unsigned short* __restrict__ pWd, const float* __restrict__ bdst,
    unsigned short* __restrict__ fs, unsigned short* __restrict__ fdB, int nrows, int nLn1,
    const int* __restrict__ dst, const int* __restrict__ srcA,
    const int* __restrict__ rs, const int* __restrict__ rank,
    int* __restrict__ srcSorted, int E, int nFill)
{
    __shared__ __align__(16) float hs[RB][132];
    __shared__ __align__(16) unsigned short pa[4 * 64 * 8];
    __shared__ float s_mu[RB], s_rs[RB];

    // role assignment: interleave fill/ln1 by parity over the paired range
    const int nPair = 2 * (nLn1 < nFill ? nLn1 : nFill);
    bool isFill;
    int idx;
    if ((int)blockIdx.x < nPair) {
        isFill = (blockIdx.x & 1);
        idx = blockIdx.x >> 1;
    } else {
        int r = blockIdx.x - nPair;
        isFill = (nFill > nLn1);
        idx = (nLn1 < nFill ? nLn1 : nFill) + r;
    }

    if (isFill) {
        int e = idx * 256 + threadIdx.x;
        if (e < E) srcSorted[rs[dst[e]] + rank[e]] = srcA[e];
        return;
    }

    const int tid  = threadIdx.x;
    const int row0 = idx * RB;
    const int lane = tid & 63;
    const int w    = tid >> 6;

    #pragma unroll
    for (int i = 0; i < 2; ++i) {
        int f   = tid + i * 256;
        int row = f >> 5;
        int c0  = (f & 31) * 4;
        float4 v = make_float4(0.f, 0.f, 0.f, 0.f);
        if (row0 + row < nrows) v = *(const float4*)(x + (size_t)(row0 + row) * 128 + c0);
        *(float4*)&hs[row][c0] = v;
    }
    __syncthreads();

    {
        const int ln = lane;
        #pragma unroll
        for (int rr = 0; rr < 4; ++rr) {
            int row = w * 4 + rr;
            float v0 = hs[row][ln * 2], v1 = hs[row][ln * 2 + 1];
            float s = v0 + v1, sq = v0 * v0 + v1 * v1;
            #pragma unroll
            for (int m = 32; m; m >>= 1) { s += __shfl_xor(s, m); sq += __shfl_xor(sq, m); }
            if (ln == 0) {
                float mu  = s * (1.0f / 128.0f);
                float var = sq * (1.0f / 128.0f) - mu * mu;
                s_mu[row] = mu;
                s_rs[row] = rsqrtf(var + LN_EPS);
            }
        }
    }
    __syncthreads();

    {
        const int kt  = w;
        const int row = lane & 15;
        const int k0  = kt * 32 + 8 * (lane >> 4);
        float mu = s_mu[row], rs2 = s_rs[row];
        float4 u  = *(float4*)&hs[row][k0];
        float4 v  = *(float4*)&hs[row][k0 + 4];
        float4 g0 = *(const float4*)&ln_g[k0];
        float4 g1 = *(const float4*)&ln_g[k0 + 4];
        float4 c0 = *(const float4*)&ln_b[k0];
        float4 c1 = *(const float4*)&ln_b[k0 + 4];
        short8v pv;
        pv[0] = (short)f2bf((u.x - mu) * rs2 * g0.x + c0.x);
        pv[1] = (short)f2bf((u.y - mu) * rs2 * g0.y + c0.y);
        pv[2] = (short)f2bf((u.z - mu) * rs2 * g0.z + c0.z);
        pv[3] = (short)f2bf((u.w - mu) * rs2 * g0.w + c0.w);
        pv[4] = (short)f2bf((v.x - mu) * rs2 * g1.x + c1.x);
        pv[5] = (short)f2bf((v.y - mu) * rs2 * g1.y + c1.y);
        pv[6] = (short)f2bf((v.z - mu) * rs2 * g1.z + c1.z);
        pv[7] = (short)f2bf((v.w - mu) * rs2 * g1.w + c1.w);
        *(short8v*)&pa[(kt * 64 + lane) * 8] = pv;
    }
    __syncthreads();

    short8v a[4];
    #pragma unroll
    for (int kt = 0; kt < 4; ++kt)
        a[kt] = *(const short8v*)&pa[(kt * 64 + lane) * 8];

    #pragma unroll
    for (int j = 0; j < 2; ++j) {
        const int nt = 2 * w + j;
        floatx4 aS = {0.f, 0.f, 0.f, 0.f};
        floatx4 aD = {0.f, 0.f, 0.f, 0.f};
        #pragma unroll
        for (int kt = 0; kt < 4; ++kt) {
            short8v bS = *(const short8v*)(pWs + (size_t)((nt * 4 + kt) * 64 + lane) * 8);
            aS = __builtin_amdgcn_mfma_f32_16x16x32_bf16(a[kt], bS, aS, 0, 0, 0);
            short8v bD = *(const short8v*)(pWd + (size_t)((nt * 4 + kt) * 64 + lane) * 8);
            aD = __builtin_amdgcn_mfma_f32_16x16x32_bf16(a[kt], bD, aD, 0, 0, 0);
        }
        const int col = nt * 16 + (lane & 15);
        const int hh  = col >> 5, hd = col & 31;
        const float bS0 = bsrc[col], bD0 = bdst[col];
        #pragma unroll
        for (int r = 0; r < 4; ++r) {
            int grow = row0 + 4 * (lane >> 4) + r;
            if (grow < nrows) {
                size_t po = ((size_t)hh * nrows + grow) * 32 + hd;   // [H][N][32]
                fs [po] = f2bf(aS[r] + bS0);
                fdB[po] = f2bf(aD[r] + bD0);
            }
        }
    }
}

// ---------------------------------------------------------------------------
// GAT gather, per-(node,head) wave, head-major grid. fs/fdB are [H][N][32].
// 8 edge-slots/wave (8 lanes x 4 dims each), 2-deep pipeline, pk-f32 math.
// Writes hmid slice (32 dims) as BF16.
// ---------------------------------------------------------------------------
__global__ __launch_bounds__(256) void gat_gather(
    const unsigned short* __restrict__ fs, const unsigned short* __restrict__ fdB,
    unsigned short* __restrict__ hm, const float* __restrict__ x,
    const int* __restrict__ srcSorted, const int* __restrict__ rs,
    const float* __restrict__ attn, const float* __restrict__ gat_bias,
    const int* __restrict__ gid, const float* __restrict__ tc, int N)
{
    const int lane = threadIdx.x & 63;
    const int wib  = threadIdx.x >> 6;
    const int wi   = blockIdx.x * 4 + wib;     // head-major: h = wi/N
    if (wi >= N * 4) return;
    const int h = wi / N;
    const int n = wi - h * N;

    const int g  = lane >> 3;      // edge slot 0..7
    const int l8 = lane & 7;
    const int d  = l8 * 4;         // dims within head [0,32)

    const size_t hb = (size_t)h * N;

    f32x2 c1v[2], c2v[2], vdv[2];
    {
        float4 a4 = *(const float4*)(attn + h * 32 + d);
        c1v[0].x = 0.6f * a4.x; c1v[0].y = 0.6f * a4.y;
        c1v[1].x = 0.6f * a4.z; c1v[1].y = 0.6f * a4.w;
        c2v[0].x = 0.4f * a4.x; c2v[0].y = 0.4f * a4.y;
        c2v[1].x = 0.4f * a4.z; c2v[1].y = 0.4f * a4.w;
        uint2 vdu = *(const uint2*)(fdB + (hb + n) * 32 + d);
        vdv[0].x = __uint_as_float(vdu.x << 16);
        vdv[0].y = __uint_as_float(vdu.x & 0xffff0000u);
        vdv[1].x = __uint_as_float(vdu.y << 16);
        vdv[1].y = __uint_as_float(vdu.y & 0xffff0000u);
    }

    const int lo = rs[n], hi = rs[n + 1];
    const int T  = (hi - lo + 7) >> 3;

    float den = 0.f;
    f32x2 wv[2] = {{0.f, 0.f}, {0.f, 0.f}};

    int i = lo + g;
    bool vA = (i < hi);
    int sA = vA ? srcSorted[i] : 0;
    uint2 rA = *(const uint2*)(fs + (hb + sA) * 32 + d);

    for (int t = 0; t < T; ++t) {
        const int inx = i + 8;
        const bool vB = (inx < hi);
        const int sB = vB ? srcSorted[inx] : 0;
        uint2 rB = *(const uint2*)(fs + (hb + sB) * 32 + d);   // prefetch

        f32x2 v2[2];
        v2[0].x = __uint_as_float(rA.x << 16);
        v2[0].y = __uint_as_float(rA.x & 0xffff0000u);
        v2[1].x = __uint_as_float(rA.y << 16);
        v2[1].y = __uint_as_float(rA.y & 0xffff0000u);

        f32x2 p2 = {0.f, 0.f};
        #pragma unroll
        for (int j = 0; j < 2; ++j) {
            f32x2 e = v2[j] + vdv[j];                                   // v_pk_add_f32
            p2 = __builtin_elementwise_fma(c1v[j], e, p2);              // v_pk_fma_f32
            p2 = __builtin_elementwise_fma(c2v[j],
                     __builtin_elementwise_abs(e), p2);
        }
        float p = p2.x + p2.y;
        p += __shfl_xor(p, 1);
        p += __shfl_xor(p, 2);
        p += __shfl_xor(p, 4);          // full head score across 8 lanes
        float exv = vA ? __expf(p) : 0.f;
        den += exv;
        f32x2 ex2; ex2.x = exv; ex2.y = exv;
        wv[0] = __builtin_elementwise_fma(ex2, v2[0], wv[0]);
        wv[1] = __builtin_elementwise_fma(ex2, v2[1], wv[1]);

        vA = vB; rA = rB; i = inx;
    }

    float w0 = wv[0].x, w1 = wv[0].y, w2 = wv[1].x, w3 = wv[1].y;

    // merge 8 edge slots (lanes with same l8 across slots)
    den += __shfl_xor(den, 8);  den += __shfl_xor(den, 16); den += __shfl_xor(den, 32);
    w0  += __shfl_xor(w0, 8);   w0  += __shfl_xor(w0, 16);  w0  += __shfl_xor(w0, 32);
    w1  += __shfl_xor(w1, 8);   w1  += __shfl_xor(w1, 16);  w1  += __shfl_xor(w1, 32);
    w2  += __shfl_xor(w2, 8);   w2  += __shfl_xor(w2, 16);  w2  += __shfl_xor(w2, 32);
    w3  += __shfl_xor(w3, 8);   w3  += __shfl_xor(w3, 16);  w3  += __shfl_xor(w3, 32);

    if (g == 0) {
        const float inv = den > 0.f ? 1.0f / den : 0.f;
        const int gg = gid[n];
        const int c0 = h * 32 + d;
        float4 x4 = *(const float4*)(x  + (size_t)n * 128 + c0);
        float4 t4 = *(const float4*)(tc + (size_t)gg * 128 + c0);
        float4 g4 = *(const float4*)(gat_bias + c0);
        float o0 = gelu_erf(w0 * inv + g4.x) + t4.x + x4.x;
        float o1 = gelu_erf(w1 * inv + g4.y) + t4.y + x4.y;
        float o2 = gelu_erf(w2 * inv + g4.z) + t4.z + x4.z;
        float o3 = gelu_erf(w3 * inv + g4.w) + t4.w + x4.w;
        uint2 pk;
        pk.x = (unsigned int)f2bf(o0) | ((unsigned int)f2bf(o1) << 16);
        pk.y = (unsigned int)f2bf(o2) | ((unsigned int)f2bf(o3) << 16);
        *(uint2*)(hm + (size_t)n * 128 + c0) = pk;
    }
}

// ---------------------------------------------------------------------------
// LN2 + FFN via MFMA. 16 rows/block, 4 waves. hmid input is BF16 [N][128].
// ---------------------------------------------------------------------------
__global__ __launch_bounds__(256) void combine_ffn(
    const unsigned short* __restrict__ hmg,
    const float* __restrict__ ln_g, const float* __restrict__ ln_b,
    const unsigned short* __restrict__ pW1, const float* __restrict__ b1,
    const unsigned short* __restrict__ pW2, const float* __restrict__ b2,
    float* __restrict__ out, int nrows)
{
    __shared__ __align__(16) float hs[RB][132];
    __shared__ __align__(16) unsigned short pa[4 * 64 * 8];
    __shared__ __align__(16) unsigned short a2[RB * 264];
    __shared__ float s_mu[RB], s_rs[RB];

    const int tid  = threadIdx.x;
    const int row0 = blockIdx.x * RB;
    const int lane = tid & 63;
    const int w    = tid >> 6;

    {
        int row = tid >> 4;
        int c0  = (tid & 15) * 8;
        uint4 u = make_uint4(0, 0, 0, 0);
        if (row0 + row < nrows) u = *(const uint4*)(hmg + (size_t)(row0 + row) * 128 + c0);
        float* hr = &hs[row][c0];
        hr[0] = __uint_as_float(u.x << 16);
        hr[1] = __uint_as_float(u.x & 0xffff0000u);
        hr[2] = __uint_as_float(u.y << 16);
        hr[3] = __uint_as_float(u.y & 0xffff0000u);
        hr[4] = __uint_as_float(u.z << 16);
        hr[5] = __uint_as_float(u.z & 0xffff0000u);
        hr[6] = __uint_as_float(u.w << 16);
        hr[7] = __uint_as_float(u.w & 0xffff0000u);
    }
    __syncthreads();

    {
        const int ln = lane;
        #pragma unroll
        for (int rr = 0; rr < 4; ++rr) {
            int row = w * 4 + rr;
            float v0 = hs[row][ln * 2], v1 = hs[row][ln * 2 + 1];
            float s = v0 + v1, sq = v0 * v0 + v1 * v1;
            #pragma unroll
            for (int m = 32; m; m >>= 1) { s += __shfl_xor(s, m); sq += __shfl_xor(sq, m); }
            if (ln == 0) {
                float mu  = s * (1.0f / 128.0f);
                float var = sq * (1.0f / 128.0f) - mu * mu;
                s_mu[row] = mu;
                s_rs[row] = rsqrtf(var + LN_EPS);
            }
        }
    }
    __syncthreads();

    {
        const int kt  = w;
        const int row = lane & 15;
        const int k0  = kt * 32 + 8 * (lane >> 4);
        float mu = s_mu[row], rs2 = s_rs[row];
        float4 u  = *(float4*)&hs[row][k0];
        float4 v  = *(float4*)&hs[row][k0 + 4];
        float4 g0 = *(const float4*)&ln_g[k0];
        float4 g1 = *(const float4*)&ln_g[k0 + 4];
        float4 c0 = *(const float4*)&ln_b[k0];
        float4 c1 = *(const float4*)&ln_b[k0 + 4];
        short8v pv;
        pv[0] = (short)f2bf((u.x - mu) * rs2 * g0.x + c0.x);
        pv[1] = (short)f2bf((u.y - mu) * rs2 * g0.y + c0.y);
        pv[2] = (short)f2bf((u.z - mu) * rs2 * g0.z + c0.z);
        pv[3] = (short)f2bf((u.w - mu) * rs2 * g0.w + c0.w);
        pv[4] = (short)f2bf((v.x - mu) * rs2 * g1.x + c1.x);
        pv[5] = (short)f2bf((v.y - mu) * rs2 * g1.y + c1.y);
        pv[6] = (short)f2bf((v.z - mu) * rs2 * g1.z + c1.z);
        pv[7] = (short)f2bf((v.w - mu) * rs2 * g1.w + c1.w);
        *(short8v*)&pa[(kt * 64 + lane) * 8] = pv;
    }
    __syncthreads();

    {
        short8v a[4];
        #pragma unroll
        for (int kt = 0; kt < 4; ++kt)
            a[kt] = *(const short8v*)&pa[(kt * 64 + lane) * 8];

        #pragma unroll
        for (int jj = 0; jj < 4; ++jj) {
            const int nt = 4 * w + jj;
            floatx4 acc = {0.f, 0.f, 0.f, 0.f};
            #pragma unroll
            for (int kt = 0; kt < 4; ++kt) {
                short8v b = *(const short8v*)(pW1 + (size_t)((nt * 4 + kt) * 64 + lane) * 8);
                acc = __builtin_amdgcn_mfma_f32_16x16x32_bf16(a[kt], b, acc, 0, 0, 0);
            }
            const int col = nt * 16 + (lane & 15);
            const float bb = b1[col];
            #pragma unroll
            for (int r = 0; r < 4; ++r) {
                int rowD = 4 * (lane >> 4) + r;
                a2[rowD * 264 + col] = f2bf(gelu_erf(acc[r] + bb));
            }
        }
    }
    __syncthreads();

    {
        floatx4 acc2[2] = {{0.f, 0.f, 0.f, 0.f}, {0.f, 0.f, 0.f, 0.f}};
        #pragma unroll
        for (int kt = 0; kt < 8; ++kt) {
            short8v af = *(const short8v*)&a2[(lane & 15) * 264 + kt * 32 + 8 * (lane >> 4)];
            #pragma unroll
            for (int j = 0; j < 2; ++j) {
                const int nt = 2 * w + j;
                short8v b = *(const short8v*)(pW2 + (size_t)((nt * 8 + kt) * 64 + lane) * 8);
                acc2[j] = __builtin_amdgcn_mfma_f32_16x16x32_bf16(af, b, acc2[j], 0, 0, 0);
            }
        }
        #pragma unroll
        for (int j = 0; j < 2; ++j) {
            const int col = (2 * w + j) * 16 + (lane & 15);
            const float bb = b2[col];
            #pragma unroll
            for (int r = 0; r < 4; ++r) {
                int rowD = 4 * (lane >> 4) + r;
                int grow = row0 + rowD;
                if (grow < nrows)
                    out[(size_t)grow * 128 + col] = hs[rowD][col] + acc2[j][r] + bb;
            }
        }
    }
}

// ---------------------------------------------------------------------------
extern "C" void kernel_launch(void* const* d_in, const int* in_sizes, int n_in,
                              void* d_out, int out_size, void* d_ws, size_t ws_size,
                              hipStream_t stream)
{
    const float* x    = (const float*)d_in[0];
    const int*   src  = (const int*)  d_in[1];
    const int*   dst  = (const int*)  d_in[2];
    const int*   gid  = (const int*)  d_in[3];
    const float* temb = (const float*)d_in[4];
    const float* Wsrc = (const float*)d_in[5];
    const float* bsrc = (const float*)d_in[6];
    const float* Wdst = (const float*)d_in[7];
    const float* bdst = (const float*)d_in[8];
    const float* attn = (const float*)d_in[9];
    const float* gbias= (const float*)d_in[10];
    const float* ln1g = (const float*)d_in[11];
    const float* ln1b = (const float*)d_in[12];
    const float* ln2g = (const float*)d_in[13];
    const float* ln2b = (const float*)d_in[14];
    const float* tW   = (const float*)d_in[15];
    const float* tb   = (const float*)d_in[16];
    const float* W1   = (const float*)d_in[17];
    const float* b1   = (const float*)d_in[18];
    const float* W2   = (const float*)d_in[19];
    const float* b2   = (const float*)d_in[20];

    const int N = in_sizes[0] / 128;
    const int E = in_sizes[1];
    const int B = in_sizes[4] / 128;
    float* out = (float*)d_out;

    char* ws = (char*)d_ws;
    size_t off = 0;
    auto alloc = [&](size_t bytes) { void* p = ws + off; off += (bytes + 255) & ~(size_t)255; return p; };
    unsigned short* fs  = (unsigned short*)alloc((size_t)N * 128 * 2);  // bf16 [H][N][32]
    unsigned short* fdB = (unsigned short*)alloc((size_t)N * 128 * 2);  // bf16 [H][N][32]
    unsigned short* hm  = (unsigned short*)alloc((size_t)N * 128 * 2);  // bf16 hmid [N][128]
    int*   deg          = (int*)           alloc((size_t)N * 4);
    int*   rsb          = (int*)           alloc((size_t)(N + 1) * 4);
    int*   rank         = (int*)           alloc((size_t)E * 4);
    int*   srcSorted    = (int*)           alloc((size_t)E * 4);
    float* tc           = (float*)         alloc((size_t)B * 128 * 4);
    int*   btot         = (int*)           alloc((size_t)1024 * 4);
    unsigned short* pWs = (unsigned short*)alloc((size_t)128 * 128 * 2);
    unsigned short* pWd = (unsigned short*)alloc((size_t)128 * 128 * 2);
    unsigned short* pW1 = (unsigned short*)alloc((size_t)128 * 256 * 2);
    unsigned short* pW2 = (unsigned short*)alloc((size_t)256 * 128 * 2);

    const int nbScan = (N + 1023) >> 10;     // 98 (<=128 required by scan_tops)
    const int nRank  = (E + 255) / 256;      // 6250
    const int nLn1   = (N + RB - 1) / RB;    // 6250
    const int nFill  = (E + 255) / 256;      // 6250

    hipMemsetAsync(deg, 0, (size_t)N * 4, stream);
    prep<<<nRank + 49, 256, 0, stream>>>(dst, deg, rank, E, nRank,
        temb, tW, tb, tc, B, Wsrc, pWs, Wdst, pWd, W1, pW1, W2, pW2);
    scan_blocks<<<nbScan, 256, 0, stream>>>(deg, rsb, btot, N);
    scan_tops<<<1, 64, 0, stream>>>(btot, nbScan, rsb, N, E);
    scan_add<<<(N + 255) / 256, 256, 0, stream>>>(rsb, btot, N);
    ln1_fill<<<nLn1 + nFill, 256, 0, stream>>>(
        x, ln1g, ln1b, pWs, bsrc, pWd, bdst, fs, fdB, N, nLn1,
        dst, src, rsb, rank, srcSorted, E, nFill);
    gat_gather<<<(N * 4 + 3) / 4, 256, 0, stream>>>(
        fs, fdB, hm, x, srcSorted, rsb, attn, gbias, gid, tc, N);
    combine_ffn<<<(N + RB - 1) / RB, 256, 0, stream>>>(
        hm, ln2g, ln2b, pW1, b1, pW2, b2, out, N);
}

// Round 13
// 271.216 us; speedup vs baseline: 1.4267x; 1.4267x over previous
//
#include <hip/hip_runtime.h>
#include <hip/hip_bf16.h>

// ResidualGATBlock: LN1 -> GATv2(4 heads) -> gelu -> +time_cond +x -> LN2 -> FFN -> residual
// N=100000, E=1600000, D=128, H=4, HD=32, B=8, TD=128. f32 I/O.
// Round 13: revert round-12's per-head gather (4x edge-walk + 64B rows made
// it 2.3x slower). Gather = round-11 design ([N][128], 4 edges/wave).
// Keep r12's parity-interleaved ln1/fill to isolate its effect.

#define RB 16
#define NEG_SLOPE 0.2f
#define LN_EPS 1e-5f

typedef __attribute__((ext_vector_type(8))) short short8v;   // 8 bf16 (4 VGPRs)
typedef __attribute__((ext_vector_type(4))) float floatx4;   // MFMA accum
typedef __attribute__((ext_vector_type(2))) float f32x2;     // packed f32 (VOP3P)

__device__ __forceinline__ float gelu_erf(float v) {
    return 0.5f * v * (1.0f + erff(v * 0.70710678118654752f));
}
__device__ __forceinline__ unsigned short f2bf(float f) {    // RNE f32->bf16
    unsigned int u = __float_as_uint(f);
    u += 0x7fffu + ((u >> 16) & 1u);
    return (unsigned short)(u >> 16);
}

// ---------------------------------------------------------------------------
// pack W [K][C] f32 row-major -> bf16 B-fragments for mfma_f32_16x16x32_bf16.
// ---------------------------------------------------------------------------
__device__ __forceinline__ void pack_region(
    const float* __restrict__ W, unsigned short* __restrict__ P, int K, int C, int idx)
{
    int total = (K >> 5) * (C >> 4) * 64;
    if (idx >= total) return;
    int lane = idx & 63;
    int f = idx >> 6;
    int nkt = K >> 5;
    int nt = f / nkt, kt = f - nt * nkt;
    int col = nt * 16 + (lane & 15);
    int k0 = kt * 32 + 8 * (lane >> 4);
    short8v v;
    #pragma unroll
    for (int i = 0; i < 8; ++i)
        v[i] = (short)f2bf(W[(size_t)(k0 + i) * C + col]);
    *(short8v*)(P + (size_t)idx * 8) = v;
}

// ---------------------------------------------------------------------------
// prep: blocks [0,nRank) = csr_rank; then 1 time_mlp + 48 pack blocks.
// deg pre-zeroed by memsetAsync.
// ---------------------------------------------------------------------------
__global__ __launch_bounds__(256) void prep(
    const int* __restrict__ dst, int* __restrict__ deg, int* __restrict__ rank,
    int E, int nRank,
    const float* __restrict__ temb, const float* __restrict__ tW,
    const float* __restrict__ tb, float* __restrict__ tc, int B,
    const float* __restrict__ Wsrc, unsigned short* __restrict__ pWs,
    const float* __restrict__ Wdst, unsigned short* __restrict__ pWd,
    const float* __restrict__ W1,   unsigned short* __restrict__ pW1,
    const float* __restrict__ W2,   unsigned short* __restrict__ pW2)
{
    const int t = threadIdx.x;
    if (blockIdx.x < nRank) {
        int e = blockIdx.x * 256 + t;
        if (e < E) rank[e] = atomicAdd(&deg[dst[e]], 1);
        return;
    }
    const int bid = blockIdx.x - nRank;
    if (bid == 0) {
        __shared__ float te[8 * 128];
        for (int i = t; i < B * 128; i += 256) te[i] = temb[i];
        __syncthreads();
        int c = t & 127, half = t >> 7;
        for (int b = half * 4; b < half * 4 + 4; ++b) {
            if (b >= B) break;
            float acc = 0.f;
            for (int k = 0; k < 128; ++k) acc = fmaf(te[b * 128 + k], tW[k * 128 + c], acc);
            tc[b * 128 + c] = gelu_erf(acc + tb[c]);
        }
    } else if (bid < 9) {
        pack_region(Wsrc, pWs, 128, 128, (bid - 1) * 256 + t);
    } else if (bid < 17) {
        pack_region(Wdst, pWd, 128, 128, (bid - 9) * 256 + t);
    } else if (bid < 33) {
        pack_region(W1, pW1, 128, 256, (bid - 17) * 256 + t);
    } else {
        pack_region(W2, pW2, 256, 128, (bid - 33) * 256 + t);
    }
}

// ---------------------------------------------------------------------------
// Parallel scan (3 phases)
// ---------------------------------------------------------------------------
__global__ __launch_bounds__(256) void scan_blocks(
    const int* __restrict__ deg, int* __restrict__ rs, int* __restrict__ btot, int N)
{
    __shared__ int wtot[4];
    const int t    = threadIdx.x;
    const int idx  = blockIdx.x * 1024 + t * 4;
    int d0 = 0, d1 = 0, d2 = 0, d3 = 0;
    if (idx + 3 < N) {
        int4 v = *(const int4*)(deg + idx);
        d0 = v.x; d1 = v.y; d2 = v.z; d3 = v.w;
    } else {
        if (idx     < N) d0 = deg[idx];
        if (idx + 1 < N) d1 = deg[idx + 1];
        if (idx + 2 < N) d2 = deg[idx + 2];
        if (idx + 3 < N) d3 = deg[idx + 3];
    }
    const int ts = d0 + d1 + d2 + d3;
    const int lane = t & 63, w = t >> 6;
    int incl = ts;
    #pragma unroll
    for (int m = 1; m < 64; m <<= 1) { int u = __shfl_up(incl, m); if (lane >= m) incl += u; }
    if (lane == 63) wtot[w] = incl;
    __syncthreads();
    int woff = 0;
    #pragma unroll
    for (int i = 0; i < 4; ++i) woff += (i < w) ? wtot[i] : 0;
    const int p = woff + incl - ts;
    if (idx + 3 < N) {
        int4 o;
        o.x = p; o.y = p + d0; o.z = p + d0 + d1; o.w = p + d0 + d1 + d2;
        *(int4*)(rs + idx) = o;
    } else {
        if (idx     < N) rs[idx]     = p;
        if (idx + 1 < N) rs[idx + 1] = p + d0;
        if (idx + 2 < N) rs[idx + 2] = p + d0 + d1;
        if (idx + 3 < N) rs[idx + 3] = p + d0 + d1 + d2;
    }
    if (t == 255) btot[blockIdx.x] = woff + incl;
}

__global__ __launch_bounds__(64) void scan_tops(
    int* __restrict__ btot, int nb, int* __restrict__ rs, int N, int E)
{
    const int lane = threadIdx.x;
    int a0 = (2 * lane     < nb) ? btot[2 * lane]     : 0;
    int a1 = (2 * lane + 1 < nb) ? btot[2 * lane + 1] : 0;
    const int ts = a0 + a1;
    int incl = ts;
    #pragma unroll
    for (int m = 1; m < 64; m <<= 1) { int u = __shfl_up(incl, m); if (lane >= m) incl += u; }
    const int ex = incl - ts;
    if (2 * lane     < nb) btot[2 * lane]     = ex;
    if (2 * lane + 1 < nb) btot[2 * lane + 1] = ex + a0;
    if (lane == 0) rs[N] = E;
}

__global__ __launch_bounds__(256) void scan_add(
    int* __restrict__ rs, const int* __restrict__ btot, int N)
{
    int i = blockIdx.x * 256 + threadIdx.x;
    if (i < N) rs[i] += btot[i >> 10];
}

// ---------------------------------------------------------------------------
// Fused ln1 + fill, roles interleaved by block parity (fill blocks co-reside
// with GEMM blocks on each CU). fs/fdB written [N][128] bf16.
// ---------------------------------------------------------------------------
__global__ __launch_bounds__(256) void ln1_fill(
    const float* __restrict__ x,
    const float* __restrict__ ln_g, const float* __restrict__ ln_b,
    const unsigned short* __restrict__ pWs, const float* __restrict__ bsrc,
    const unsigned short* __restrict__ pWd, const float* __restrict__ bdst,
    unsigned short* __restrict__ fs, unsigned short* __restrict__ fdB, int nrows, int nLn1,
    const int* __restrict__ dst, const int* __restrict__ srcA,
    const int* __restrict__ rs, const int* __restrict__ rank,
    int* __restrict__ srcSorted, int E, int nFill)
{
    __shared__ __align__(16) float hs[RB][132];
    __shared__ __align__(16) unsigned short pa[4 * 64 * 8];
    __shared__ float s_mu[RB], s_rs[RB];

    const int nPair = 2 * (nLn1 < nFill ? nLn1 : nFill);
    bool isFill;
    int idx;
    if ((int)blockIdx.x < nPair) {
        isFill = (blockIdx.x & 1);
        idx = blockIdx.x >> 1;
    } else {
        int r = blockIdx.x - nPair;
        isFill = (nFill > nLn1);
        idx = (nLn1 < nFill ? nLn1 : nFill) + r;
    }

    if (isFill) {
        int e = idx * 256 + threadIdx.x;
        if (e < E) srcSorted[rs[dst[e]] + rank[e]] = srcA[e];
        return;
    }

    const int tid  = threadIdx.x;
    const int row0 = idx * RB;
    const int lane = tid & 63;
    const int w    = tid >> 6;

    #pragma unroll
    for (int i = 0; i < 2; ++i) {
        int f   = tid + i * 256;
        int row = f >> 5;
        int c0  = (f & 31) * 4;
        float4 v = make_float4(0.f, 0.f, 0.f, 0.f);
        if (row0 + row < nrows) v = *(const float4*)(x + (size_t)(row0 + row) * 128 + c0);
        *(float4*)&hs[row][c0] = v;
    }
    __syncthreads();

    {
        const int ln = lane;
        #pragma unroll
        for (int rr = 0; rr < 4; ++rr) {
            int row = w * 4 + rr;
            float v0 = hs[row][ln * 2], v1 = hs[row][ln * 2 + 1];
            float s = v0 + v1, sq = v0 * v0 + v1 * v1;
            #pragma unroll
            for (int m = 32; m; m >>= 1) { s += __shfl_xor(s, m); sq += __shfl_xor(sq, m); }
            if (ln == 0) {
                float mu  = s * (1.0f / 128.0f);
                float var = sq * (1.0f / 128.0f) - mu * mu;
                s_mu[row] = mu;
                s_rs[row] = rsqrtf(var + LN_EPS);
            }
        }
    }
    __syncthreads();

    {
        const int kt  = w;
        const int row = lane & 15;
        const int k0  = kt * 32 + 8 * (lane >> 4);
        float mu = s_mu[row], rs2 = s_rs[row];
        float4 u  = *(float4*)&hs[row][k0];
        float4 v  = *(float4*)&hs[row][k0 + 4];
        float4 g0 = *(const float4*)&ln_g[k0];
        float4 g1 = *(const float4*)&ln_g[k0 + 4];
        float4 c0 = *(const float4*)&ln_b[k0];
        float4 c1 = *(const float4*)&ln_b[k0 + 4];
        short8v pv;
        pv[0] = (short)f2bf((u.x - mu) * rs2 * g0.x + c0.x);
        pv[1] = (short)f2bf((u.y - mu) * rs2 * g0.y + c0.y);
        pv[2] = (short)f2bf((u.z - mu) * rs2 * g0.z + c0.z);
        pv[3] = (short)f2bf((u.w - mu) * rs2 * g0.w + c0.w);
        pv[4] = (short)f2bf((v.x - mu) * rs2 * g1.x + c1.x);
        pv[5] = (short)f2bf((v.y - mu) * rs2 * g1.y + c1.y);
        pv[6] = (short)f2bf((v.z - mu) * rs2 * g1.z + c1.z);
        pv[7] = (short)f2bf((v.w - mu) * rs2 * g1.w + c1.w);
        *(short8v*)&pa[(kt * 64 + lane) * 8] = pv;
    }
    __syncthreads();

    short8v a[4];
    #pragma unroll
    for (int kt = 0; kt < 4; ++kt)
        a[kt] = *(const short8v*)&pa[(kt * 64 + lane) * 8];

    #pragma unroll
    for (int j = 0; j < 2; ++j) {
        const int nt = 2 * w + j;
        floatx4 aS = {0.f, 0.f, 0.f, 0.f};
        floatx4 aD = {0.f, 0.f, 0.f, 0.f};
        #pragma unroll
        for (int kt = 0; kt < 4; ++kt) {
            short8v bS = *(const short8v*)(pWs + (size_t)((nt * 4 + kt) * 64 + lane) * 8);
            aS = __builtin_amdgcn_mfma_f32_16x16x32_bf16(a[kt], bS, aS, 0, 0, 0);
            short8v bD = *(const short8v*)(pWd + (size_t)((nt * 4 + kt) * 64 + lane) * 8);
            aD = __builtin_amdgcn_mfma_f32_16x16x32_bf16(a[kt], bD, aD, 0, 0, 0);
        }
        const int col = nt * 16 + (lane & 15);
        const float bS0 = bsrc[col], bD0 = bdst[col];
        #pragma unroll
        for (int r = 0; r < 4; ++r) {
            int grow = row0 + 4 * (lane >> 4) + r;
            if (grow < nrows) {
                fs [(size_t)grow * 128 + col] = f2bf(aS[r] + bS0);
                fdB[(size_t)grow * 128 + col] = f2bf(aD[r] + bD0);
            }
        }
    }
}

// ---------------------------------------------------------------------------
// GAT gather (round-11 design): one wave/node, 4 edges/iter (16 lanes x 8
// dims), 2-deep pipeline, pk-f32 math, [N][128] bf16 fs/fdB. hmid bf16.
// ---------------------------------------------------------------------------
__global__ __launch_bounds__(256) void gat_gather(
    const unsigned short* __restrict__ fs, const unsigned short* __restrict__ fdB,
    unsigned short* __restrict__ hm, const float* __restrict__ x,
    const int* __restrict__ srcSorted, const int* __restrict__ rs,
    const float* __restrict__ attn, const float* __restrict__ gat_bias,
    const int* __restrict__ gid, const float* __restrict__ tc, int N)
{
    const int lane = threadIdx.x & 63;
    const int wib  = threadIdx.x >> 6;
    const int n    = blockIdx.x * 4 + wib;
    if (n >= N) return;

    const int g   = lane >> 4;     // edge slot 0..3
    const int l16 = lane & 15;
    const int d0  = l16 * 8;       // 8 dims per lane

    f32x2 c1v[4], c2v[4], vdv[4];
    {
        float4 a0 = *(const float4*)(attn + d0);
        float4 a1 = *(const float4*)(attn + d0 + 4);
        float av[8] = {a0.x, a0.y, a0.z, a0.w, a1.x, a1.y, a1.z, a1.w};
        uint4 vdu = *(const uint4*)(fdB + (size_t)n * 128 + d0);
        unsigned int uu[4] = {vdu.x, vdu.y, vdu.z, vdu.w};
        #pragma unroll
        for (int j = 0; j < 4; ++j) {
            c1v[j].x = 0.6f * av[2 * j];     c1v[j].y = 0.6f * av[2 * j + 1];
            c2v[j].x = 0.4f * av[2 * j];     c2v[j].y = 0.4f * av[2 * j + 1];
            vdv[j].x = __uint_as_float(uu[j] << 16);
            vdv[j].y = __uint_as_float(uu[j] & 0xffff0000u);
        }
    }

    const int lo = rs[n], hi = rs[n + 1];
    const int T  = (hi - lo + 3) >> 2;

    float den = 0.f;
    f32x2 wv[4] = {{0.f, 0.f}, {0.f, 0.f}, {0.f, 0.f}, {0.f, 0.f}};

    int i = lo + g;
    bool vA = (i < hi);
    int sA = vA ? srcSorted[i] : 0;
    uint4 rA = *(const uint4*)(fs + (size_t)sA * 128 + d0);

    for (int t = 0; t < T; ++t) {
        const int inx = i + 4;
        const bool vB = (inx < hi);
        const int sB = vB ? srcSorted[inx] : 0;
        uint4 rB = *(const uint4*)(fs + (size_t)sB * 128 + d0);   // prefetch

        unsigned int ru[4] = {rA.x, rA.y, rA.z, rA.w};
        f32x2 v2[4];
        #pragma unroll
        for (int j = 0; j < 4; ++j) {
            v2[j].x = __uint_as_float(ru[j] << 16);
            v2[j].y = __uint_as_float(ru[j] & 0xffff0000u);
        }

        f32x2 p2 = {0.f, 0.f};
        #pragma unroll
        for (int j = 0; j < 4; ++j) {
            f32x2 e = v2[j] + vdv[j];                                   // v_pk_add_f32
            p2 = __builtin_elementwise_fma(c1v[j], e, p2);              // v_pk_fma_f32
            p2 = __builtin_elementwise_fma(c2v[j],
                     __builtin_elementwise_abs(e), p2);
        }
        float p = p2.x + p2.y;
        p += __shfl_xor(p, 1);
        p += __shfl_xor(p, 2);
        float exv = vA ? __expf(p) : 0.f;
        den += exv;
        f32x2 ex2; ex2.x = exv; ex2.y = exv;
        #pragma unroll
        for (int j = 0; j < 4; ++j)
            wv[j] = __builtin_elementwise_fma(ex2, v2[j], wv[j]);

        vA = vB; rA = rB; i = inx;
    }

    float w[8];
    #pragma unroll
    for (int j = 0; j < 4; ++j) { w[2 * j] = wv[j].x; w[2 * j + 1] = wv[j].y; }

    den += __shfl_xor(den, 16);
    den += __shfl_xor(den, 32);
    #pragma unroll
    for (int j = 0; j < 8; ++j) {
        w[j] += __shfl_xor(w[j], 16);
        w[j] += __shfl_xor(w[j], 32);
    }

    if (g == 0) {
        const float inv = den > 0.f ? 1.0f / den : 0.f;
        const int gg = gid[n];
        float4 x0 = *(const float4*)(x  + (size_t)n * 128 + d0);
        float4 x1 = *(const float4*)(x  + (size_t)n * 128 + d0 + 4);
        float4 t0 = *(const float4*)(tc + (size_t)gg * 128 + d0);
        float4 t1 = *(const float4*)(tc + (size_t)gg * 128 + d0 + 4);
        float4 g0 = *(const float4*)(gat_bias + d0);
        float4 g1 = *(const float4*)(gat_bias + d0 + 4);
        float o[8];
        o[0] = gelu_erf(w[0] * inv + g0.x) + t0.x + x0.x;
        o[1] = gelu_erf(w[1] * inv + g0.y) + t0.y + x0.y;
        o[2] = gelu_erf(w[2] * inv + g0.z) + t0.z + x0.z;
        o[3] = gelu_erf(w[3] * inv + g0.w) + t0.w + x0.w;
        o[4] = gelu_erf(w[4] * inv + g1.x) + t1.x + x1.x;
        o[5] = gelu_erf(w[5] * inv + g1.y) + t1.y + x1.y;
        o[6] = gelu_erf(w[6] * inv + g1.z) + t1.z + x1.z;
        o[7] = gelu_erf(w[7] * inv + g1.w) + t1.w + x1.w;
        uint4 pk;
        pk.x = (unsigned int)f2bf(o[0]) | ((unsigned int)f2bf(o[1]) << 16);
        pk.y = (unsigned int)f2bf(o[2]) | ((unsigned int)f2bf(o[3]) << 16);
        pk.z = (unsigned int)f2bf(o[4]) | ((unsigned int)f2bf(o[5]) << 16);
        pk.w = (unsigned int)f2bf(o[6]) | ((unsigned int)f2bf(o[7]) << 16);
        *(uint4*)(hm + (size_t)n * 128 + d0) = pk;
    }
}

// ---------------------------------------------------------------------------
// LN2 + FFN via MFMA. 16 rows/block, 4 waves. hmid input is BF16 [N][128].
// ---------------------------------------------------------------------------
__global__ __launch_bounds__(256) void combine_ffn(
    const unsigned short* __restrict__ hmg,
    const float* __restrict__ ln_g, const float* __restrict__ ln_b,
    const unsigned short* __restrict__ pW1, const float* __restrict__ b1,
    const unsigned short* __restrict__ pW2, const float* __restrict__ b2,
    float* __restrict__ out, int nrows)
{
    __shared__ __align__(16) float hs[RB][132];
    __shared__ __align__(16) unsigned short pa[4 * 64 * 8];
    __shared__ __align__(16) unsigned short a2[RB * 264];
    __shared__ float s_mu[RB], s_rs[RB];

    const int tid  = threadIdx.x;
    const int row0 = blockIdx.x * RB;
    const int lane = tid & 63;
    const int w    = tid >> 6;

    {
        int row = tid >> 4;
        int c0  = (tid & 15) * 8;
        uint4 u = make_uint4(0, 0, 0, 0);
        if (row0 + row < nrows) u = *(const uint4*)(hmg + (size_t)(row0 + row) * 128 + c0);
        float* hr = &hs[row][c0];
        hr[0] = __uint_as_float(u.x << 16);
        hr[1] = __uint_as_float(u.x & 0xffff0000u);
        hr[2] = __uint_as_float(u.y << 16);
        hr[3] = __uint_as_float(u.y & 0xffff0000u);
        hr[4] = __uint_as_float(u.z << 16);
        hr[5] = __uint_as_float(u.z & 0xffff0000u);
        hr[6] = __uint_as_float(u.w << 16);
        hr[7] = __uint_as_float(u.w & 0xffff0000u);
    }
    __syncthreads();

    {
        const int ln = lane;
        #pragma unroll
        for (int rr = 0; rr < 4; ++rr) {
            int row = w * 4 + rr;
            float v0 = hs[row][ln * 2], v1 = hs[row][ln * 2 + 1];
            float s = v0 + v1, sq = v0 * v0 + v1 * v1;
            #pragma unroll
            for (int m = 32; m; m >>= 1) { s += __shfl_xor(s, m); sq += __shfl_xor(sq, m); }
            if (ln == 0) {
                float mu  = s * (1.0f / 128.0f);
                float var = sq * (1.0f / 128.0f) - mu * mu;
                s_mu[row] = mu;
                s_rs[row] = rsqrtf(var + LN_EPS);
            }
        }
    }
    __syncthreads();

    {
        const int kt  = w;
        const int row = lane & 15;
        const int k0  = kt * 32 + 8 * (lane >> 4);
        float mu = s_mu[row], rs2 = s_rs[row];
        float4 u  = *(float4*)&hs[row][k0];
        float4 v  = *(float4*)&hs[row][k0 + 4];
        float4 g0 = *(const float4*)&ln_g[k0];
        float4 g1 = *(const float4*)&ln_g[k0 + 4];
        float4 c0 = *(const float4*)&ln_b[k0];
        float4 c1 = *(const float4*)&ln_b[k0 + 4];
        short8v pv;
        pv[0] = (short)f2bf((u.x - mu) * rs2 * g0.x + c0.x);
        pv[1] = (short)f2bf((u.y - mu) * rs2 * g0.y + c0.y);
        pv[2] = (short)f2bf((u.z - mu) * rs2 * g0.z + c0.z);
        pv[3] = (short)f2bf((u.w - mu) * rs2 * g0.w + c0.w);
        pv[4] = (short)f2bf((v.x - mu) * rs2 * g1.x + c1.x);
        pv[5] = (short)f2bf((v.y - mu) * rs2 * g1.y + c1.y);
        pv[6] = (short)f2bf((v.z - mu) * rs2 * g1.z + c1.z);
        pv[7] = (short)f2bf((v.w - mu) * rs2 * g1.w + c1.w);
        *(short8v*)&pa[(kt * 64 + lane) * 8] = pv;
    }
    __syncthreads();

    {
        short8v a[4];
        #pragma unroll
        for (int kt = 0; kt < 4; ++kt)
            a[kt] = *(const short8v*)&pa[(kt * 64 + lane) * 8];

        #pragma unroll
        for (int jj = 0; jj < 4; ++jj) {
            const int nt = 4 * w + jj;
            floatx4 acc = {0.f, 0.f, 0.f, 0.f};
            #pragma unroll
            for (int kt = 0; kt < 4; ++kt) {
                short8v b = *(const short8v*)(pW1 + (size_t)((nt * 4 + kt) * 64 + lane) * 8);
                acc = __builtin_amdgcn_mfma_f32_16x16x32_bf16(a[kt], b, acc, 0, 0, 0);
            }
            const int col = nt * 16 + (lane & 15);
            const float bb = b1[col];
            #pragma unroll
            for (int r = 0; r < 4; ++r) {
                int rowD = 4 * (lane >> 4) + r;
                a2[rowD * 264 + col] = f2bf(gelu_erf(acc[r] + bb));
            }
        }
    }
    __syncthreads();

    {
        floatx4 acc2[2] = {{0.f, 0.f, 0.f, 0.f}, {0.f, 0.f, 0.f, 0.f}};
        #pragma unroll
        for (int kt = 0; kt < 8; ++kt) {
            short8v af = *(const short8v*)&a2[(lane & 15) * 264 + kt * 32 + 8 * (lane >> 4)];
            #pragma unroll
            for (int j = 0; j < 2; ++j) {
                const int nt = 2 * w + j;
                short8v b = *(const short8v*)(pW2 + (size_t)((nt * 8 + kt) * 64 + lane) * 8);
                acc2[j] = __builtin_amdgcn_mfma_f32_16x16x32_bf16(af, b, acc2[j], 0, 0, 0);
            }
        }
        #pragma unroll
        for (int j = 0; j < 2; ++j) {
            const int col = (2 * w + j) * 16 + (lane & 15);
            const float bb = b2[col];
            #pragma unroll
            for (int r = 0; r < 4; ++r) {
                int rowD = 4 * (lane >> 4) + r;
                int grow = row0 + rowD;
                if (grow < nrows)
                    out[(size_t)grow * 128 + col] = hs[rowD][col] + acc2[j][r] + bb;
            }
        }
    }
}

// ---------------------------------------------------------------------------
extern "C" void kernel_launch(void* const* d_in, const int* in_sizes, int n_in,
                              void* d_out, int out_size, void* d_ws, size_t ws_size,
                              hipStream_t stream)
{
    const float* x    = (const float*)d_in[0];
    const int*   src  = (const int*)  d_in[1];
    const int*   dst  = (const int*)  d_in[2];
    const int*   gid  = (const int*)  d_in[3];
    const float* temb = (const float*)d_in[4];
    const float* Wsrc = (const float*)d_in[5];
    const float* bsrc = (const float*)d_in[6];
    const float* Wdst = (const float*)d_in[7];
    const float* bdst = (const float*)d_in[8];
    const float* attn = (const float*)d_in[9];
    const float* gbias= (const float*)d_in[10];
    const float* ln1g = (const float*)d_in[11];
    const float* ln1b = (const float*)d_in[12];
    const float* ln2g = (const float*)d_in[13];
    const float* ln2b = (const float*)d_in[14];
    const float* tW   = (const float*)d_in[15];
    const float* tb   = (const float*)d_in[16];
    const float* W1   = (const float*)d_in[17];
    const float* b1   = (const float*)d_in[18];
    const float* W2   = (const float*)d_in[19];
    const float* b2   = (const float*)d_in[20];

    const int N = in_sizes[0] / 128;
    const int E = in_sizes[1];
    const int B = in_sizes[4] / 128;
    float* out = (float*)d_out;

    char* ws = (char*)d_ws;
    size_t off = 0;
    auto alloc = [&](size_t bytes) { void* p = ws + off; off += (bytes + 255) & ~(size_t)255; return p; };
    unsigned short* fs  = (unsigned short*)alloc((size_t)N * 128 * 2);  // bf16 feat_src [N][128]
    unsigned short* fdB = (unsigned short*)alloc((size_t)N * 128 * 2);  // bf16 feat_dst [N][128]
    unsigned short* hm  = (unsigned short*)alloc((size_t)N * 128 * 2);  // bf16 hmid [N][128]
    int*   deg          = (int*)           alloc((size_t)N * 4);
    int*   rsb          = (int*)           alloc((size_t)(N + 1) * 4);
    int*   rank         = (int*)           alloc((size_t)E * 4);
    int*   srcSorted    = (int*)           alloc((size_t)E * 4);
    float* tc           = (float*)         alloc((size_t)B * 128 * 4);
    int*   btot         = (int*)           alloc((size_t)1024 * 4);
    unsigned short* pWs = (unsigned short*)alloc((size_t)128 * 128 * 2);
    unsigned short* pWd = (unsigned short*)alloc((size_t)128 * 128 * 2);
    unsigned short* pW1 = (unsigned short*)alloc((size_t)128 * 256 * 2);
    unsigned short* pW2 = (unsigned short*)alloc((size_t)256 * 128 * 2);

    const int nbScan = (N + 1023) >> 10;     // 98 (<=128 required by scan_tops)
    const int nRank  = (E + 255) / 256;      // 6250
    const int nLn1   = (N + RB - 1) / RB;    // 6250
    const int nFill  = (E + 255) / 256;      // 6250

    hipMemsetAsync(deg, 0, (size_t)N * 4, stream);
    prep<<<nRank + 49, 256, 0, stream>>>(dst, deg, rank, E, nRank,
        temb, tW, tb, tc, B, Wsrc, pWs, Wdst, pWd, W1, pW1, W2, pW2);
    scan_blocks<<<nbScan, 256, 0, stream>>>(deg, rsb, btot, N);
    scan_tops<<<1, 64, 0, stream>>>(btot, nbScan, rsb, N, E);
    scan_add<<<(N + 255) / 256, 256, 0, stream>>>(rsb, btot, N);
    ln1_fill<<<nLn1 + nFill, 256, 0, stream>>>(
        x, ln1g, ln1b, pWs, bsrc, pWd, bdst, fs, fdB, N, nLn1,
        dst, src, rsb, rank, srcSorted, E, nFill);
    gat_gather<<<(N + 3) / 4, 256, 0, stream>>>(
        fs, fdB, hm, x, srcSorted, rsb, attn, gbias, gid, tc, N);
    combine_ffn<<<(N + RB - 1) / RB, 256, 0, stream>>>(
        hm, ln2g, ln2b, pW1, b1, pW2, b2, out, N);
}

// Round 14
// 261.520 us; speedup vs baseline: 1.4796x; 1.0371x over previous
//
#include <hip/hip_runtime.h>
#include <hip/hip_bf16.h>

// ResidualGATBlock: LN1 -> GATv2(4 heads) -> gelu -> +time_cond +x -> LN2 -> FFN -> residual
// N=100000, E=1600000, D=128, H=4, HD=32, B=8, TD=128. f32 I/O.
// Round 14: best-of composition. Sequential ln1||fill (r11: parity hurt by
// ~10us, r13). Gather: r8 scalar-unpack math (85.8us vs pk's 90.7) with
// bf16 hmid write. prep+rank fusion, 3-phase scan, bf16-hmid FFN as r11.

#define RB 16
#define NEG_SLOPE 0.2f
#define LN_EPS 1e-5f

typedef __attribute__((ext_vector_type(8))) short short8v;   // 8 bf16 (4 VGPRs)
typedef __attribute__((ext_vector_type(4))) float floatx4;   // MFMA accum

__device__ __forceinline__ float gelu_erf(float v) {
    return 0.5f * v * (1.0f + erff(v * 0.70710678118654752f));
}
__device__ __forceinline__ unsigned short f2bf(float f) {    // RNE f32->bf16
    unsigned int u = __float_as_uint(f);
    u += 0x7fffu + ((u >> 16) & 1u);
    return (unsigned short)(u >> 16);
}

// ---------------------------------------------------------------------------
// pack W [K][C] f32 row-major -> bf16 B-fragments for mfma_f32_16x16x32_bf16.
// ---------------------------------------------------------------------------
__device__ __forceinline__ void pack_region(
    const float* __restrict__ W, unsigned short* __restrict__ P, int K, int C, int idx)
{
    int total = (K >> 5) * (C >> 4) * 64;
    if (idx >= total) return;
    int lane = idx & 63;
    int f = idx >> 6;
    int nkt = K >> 5;
    int nt = f / nkt, kt = f - nt * nkt;
    int col = nt * 16 + (lane & 15);
    int k0 = kt * 32 + 8 * (lane >> 4);
    short8v v;
    #pragma unroll
    for (int i = 0; i < 8; ++i)
        v[i] = (short)f2bf(W[(size_t)(k0 + i) * C + col]);
    *(short8v*)(P + (size_t)idx * 8) = v;
}

// ---------------------------------------------------------------------------
// prep: blocks [0,nRank) = csr_rank; then 1 time_mlp + 48 pack blocks.
// deg pre-zeroed by memsetAsync.
// ---------------------------------------------------------------------------
__global__ __launch_bounds__(256) void prep(
    const int* __restrict__ dst, int* __restrict__ deg, int* __restrict__ rank,
    int E, int nRank,
    const float* __restrict__ temb, const float* __restrict__ tW,
    const float* __restrict__ tb, float* __restrict__ tc, int B,
    const float* __restrict__ Wsrc, unsigned short* __restrict__ pWs,
    const float* __restrict__ Wdst, unsigned short* __restrict__ pWd,
    const float* __restrict__ W1,   unsigned short* __restrict__ pW1,
    const float* __restrict__ W2,   unsigned short* __restrict__ pW2)
{
    const int t = threadIdx.x;
    if (blockIdx.x < nRank) {
        int e = blockIdx.x * 256 + t;
        if (e < E) rank[e] = atomicAdd(&deg[dst[e]], 1);
        return;
    }
    const int bid = blockIdx.x - nRank;
    if (bid == 0) {
        __shared__ float te[8 * 128];
        for (int i = t; i < B * 128; i += 256) te[i] = temb[i];
        __syncthreads();
        int c = t & 127, half = t >> 7;
        for (int b = half * 4; b < half * 4 + 4; ++b) {
            if (b >= B) break;
            float acc = 0.f;
            for (int k = 0; k < 128; ++k) acc = fmaf(te[b * 128 + k], tW[k * 128 + c], acc);
            tc[b * 128 + c] = gelu_erf(acc + tb[c]);
        }
    } else if (bid < 9) {
        pack_region(Wsrc, pWs, 128, 128, (bid - 1) * 256 + t);
    } else if (bid < 17) {
        pack_region(Wdst, pWd, 128, 128, (bid - 9) * 256 + t);
    } else if (bid < 33) {
        pack_region(W1, pW1, 128, 256, (bid - 17) * 256 + t);
    } else {
        pack_region(W2, pW2, 256, 128, (bid - 33) * 256 + t);
    }
}

// ---------------------------------------------------------------------------
// Parallel scan (3 phases)
// ---------------------------------------------------------------------------
__global__ __launch_bounds__(256) void scan_blocks(
    const int* __restrict__ deg, int* __restrict__ rs, int* __restrict__ btot, int N)
{
    __shared__ int wtot[4];
    const int t    = threadIdx.x;
    const int idx  = blockIdx.x * 1024 + t * 4;
    int d0 = 0, d1 = 0, d2 = 0, d3 = 0;
    if (idx + 3 < N) {
        int4 v = *(const int4*)(deg + idx);
        d0 = v.x; d1 = v.y; d2 = v.z; d3 = v.w;
    } else {
        if (idx     < N) d0 = deg[idx];
        if (idx + 1 < N) d1 = deg[idx + 1];
        if (idx + 2 < N) d2 = deg[idx + 2];
        if (idx + 3 < N) d3 = deg[idx + 3];
    }
    const int ts = d0 + d1 + d2 + d3;
    const int lane = t & 63, w = t >> 6;
    int incl = ts;
    #pragma unroll
    for (int m = 1; m < 64; m <<= 1) { int u = __shfl_up(incl, m); if (lane >= m) incl += u; }
    if (lane == 63) wtot[w] = incl;
    __syncthreads();
    int woff = 0;
    #pragma unroll
    for (int i = 0; i < 4; ++i) woff += (i < w) ? wtot[i] : 0;
    const int p = woff + incl - ts;
    if (idx + 3 < N) {
        int4 o;
        o.x = p; o.y = p + d0; o.z = p + d0 + d1; o.w = p + d0 + d1 + d2;
        *(int4*)(rs + idx) = o;
    } else {
        if (idx     < N) rs[idx]     = p;
        if (idx + 1 < N) rs[idx + 1] = p + d0;
        if (idx + 2 < N) rs[idx + 2] = p + d0 + d1;
        if (idx + 3 < N) rs[idx + 3] = p + d0 + d1 + d2;
    }
    if (t == 255) btot[blockIdx.x] = woff + incl;
}

__global__ __launch_bounds__(64) void scan_tops(
    int* __restrict__ btot, int nb, int* __restrict__ rs, int N, int E)
{
    const int lane = threadIdx.x;
    int a0 = (2 * lane     < nb) ? btot[2 * lane]     : 0;
    int a1 = (2 * lane + 1 < nb) ? btot[2 * lane + 1] : 0;
    const int ts = a0 + a1;
    int incl = ts;
    #pragma unroll
    for (int m = 1; m < 64; m <<= 1) { int u = __shfl_up(incl, m); if (lane >= m) incl += u; }
    const int ex = incl - ts;
    if (2 * lane     < nb) btot[2 * lane]     = ex;
    if (2 * lane + 1 < nb) btot[2 * lane + 1] = ex + a0;
    if (lane == 0) rs[N] = E;
}

__global__ __launch_bounds__(256) void scan_add(
    int* __restrict__ rs, const int* __restrict__ btot, int N)
{
    int i = blockIdx.x * 256 + threadIdx.x;
    if (i < N) rs[i] += btot[i >> 10];
}

// ---------------------------------------------------------------------------
// Fused: blocks [0, nLn1) = LN1 + dual MFMA GEMM (16 rows, 4 waves);
//        blocks [nLn1, nLn1+nFill) = csr_fill scatter (sequential roles —
//        parity interleave measured -10us, r13).
// ---------------------------------------------------------------------------
__global__ __launch_bounds__(256) void ln1_fill(
    const float* __restrict__ x,
    const float* __restrict__ ln_g, const float* __restrict__ ln_b,
    const unsigned short* __restrict__ pWs, const float* __restrict__ bsrc,
    const unsigned short* __restrict__ pWd, const float* __restrict__ bdst,
    unsigned short* __restrict__ fs, unsigned short* __restrict__ fdB, int nrows, int nLn1,
    const int* __restrict__ dst, const int* __restrict__ srcA,
    const int* __restrict__ rs, const int* __restrict__ rank,
    int* __restrict__ srcSorted, int E)
{
    __shared__ __align__(16) float hs[RB][132];
    __shared__ __align__(16) unsigned short pa[4 * 64 * 8];
    __shared__ float s_mu[RB], s_rs[RB];

    if (blockIdx.x >= nLn1) {
        int e = (blockIdx.x - nLn1) * 256 + threadIdx.x;
        if (e < E) srcSorted[rs[dst[e]] + rank[e]] = srcA[e];
        return;
    }

    const int tid  = threadIdx.x;
    const int row0 = blockIdx.x * RB;
    const int lane = tid & 63;
    const int w    = tid >> 6;

    #pragma unroll
    for (int i = 0; i < 2; ++i) {
        int f   = tid + i * 256;
        int row = f >> 5;
        int c0  = (f & 31) * 4;
        float4 v = make_float4(0.f, 0.f, 0.f, 0.f);
        if (row0 + row < nrows) v = *(const float4*)(x + (size_t)(row0 + row) * 128 + c0);
        *(float4*)&hs[row][c0] = v;
    }
    __syncthreads();

    {
        const int ln = lane;
        #pragma unroll
        for (int rr = 0; rr < 4; ++rr) {
            int row = w * 4 + rr;
            float v0 = hs[row][ln * 2], v1 = hs[row][ln * 2 + 1];
            float s = v0 + v1, sq = v0 * v0 + v1 * v1;
            #pragma unroll
            for (int m = 32; m; m >>= 1) { s += __shfl_xor(s, m); sq += __shfl_xor(sq, m); }
            if (ln == 0) {
                float mu  = s * (1.0f / 128.0f);
                float var = sq * (1.0f / 128.0f) - mu * mu;
                s_mu[row] = mu;
                s_rs[row] = rsqrtf(var + LN_EPS);
            }
        }
    }
    __syncthreads();

    {
        const int kt  = w;
        const int row = lane & 15;
        const int k0  = kt * 32 + 8 * (lane >> 4);
        float mu = s_mu[row], rs2 = s_rs[row];
        float4 u  = *(float4*)&hs[row][k0];
        float4 v  = *(float4*)&hs[row][k0 + 4];
        float4 g0 = *(const float4*)&ln_g[k0];
        float4 g1 = *(const float4*)&ln_g[k0 + 4];
        float4 c0 = *(const float4*)&ln_b[k0];
        float4 c1 = *(const float4*)&ln_b[k0 + 4];
        short8v pv;
        pv[0] = (short)f2bf((u.x - mu) * rs2 * g0.x + c0.x);
        pv[1] = (short)f2bf((u.y - mu) * rs2 * g0.y + c0.y);
        pv[2] = (short)f2bf((u.z - mu) * rs2 * g0.z + c0.z);
        pv[3] = (short)f2bf((u.w - mu) * rs2 * g0.w + c0.w);
        pv[4] = (short)f2bf((v.x - mu) * rs2 * g1.x + c1.x);
        pv[5] = (short)f2bf((v.y - mu) * rs2 * g1.y + c1.y);
        pv[6] = (short)f2bf((v.z - mu) * rs2 * g1.z + c1.z);
        pv[7] = (short)f2bf((v.w - mu) * rs2 * g1.w + c1.w);
        *(short8v*)&pa[(kt * 64 + lane) * 8] = pv;
    }
    __syncthreads();

    short8v a[4];
    #pragma unroll
    for (int kt = 0; kt < 4; ++kt)
        a[kt] = *(const short8v*)&pa[(kt * 64 + lane) * 8];

    #pragma unroll
    for (int j = 0; j < 2; ++j) {
        const int nt = 2 * w + j;
        floatx4 aS = {0.f, 0.f, 0.f, 0.f};
        floatx4 aD = {0.f, 0.f, 0.f, 0.f};
        #pragma unroll
        for (int kt = 0; kt < 4; ++kt) {
            short8v bS = *(const short8v*)(pWs + (size_t)((nt * 4 + kt) * 64 + lane) * 8);
            aS = __builtin_amdgcn_mfma_f32_16x16x32_bf16(a[kt], bS, aS, 0, 0, 0);
            short8v bD = *(const short8v*)(pWd + (size_t)((nt * 4 + kt) * 64 + lane) * 8);
            aD = __builtin_amdgcn_mfma_f32_16x16x32_bf16(a[kt], bD, aD, 0, 0, 0);
        }
        const int col = nt * 16 + (lane & 15);
        const float bS0 = bsrc[col], bD0 = bdst[col];
        #pragma unroll
        for (int r = 0; r < 4; ++r) {
            int grow = row0 + 4 * (lane >> 4) + r;
            if (grow < nrows) {
                fs [(size_t)grow * 128 + col] = f2bf(aS[r] + bS0);
                fdB[(size_t)grow * 128 + col] = f2bf(aD[r] + bD0);
            }
        }
    }
}

// ---------------------------------------------------------------------------
// GAT gather (r8 scalar-unpack math — measured fastest): one wave/node,
// 4 edges/iter (16 lanes x 8 dims), 2-deep pipeline, algebraic leaky-relu.
// fs/fdB bf16 [N][128]; writes hmid bf16.
// ---------------------------------------------------------------------------
__global__ __launch_bounds__(256) void gat_gather(
    const unsigned short* __restrict__ fs, const unsigned short* __restrict__ fdB,
    unsigned short* __restrict__ hm, const float* __restrict__ x,
    const int* __restrict__ srcSorted, const int* __restrict__ rs,
    const float* __restrict__ attn, const float* __restrict__ gat_bias,
    const int* __restrict__ gid, const float* __restrict__ tc, int N)
{
    const int lane = threadIdx.x & 63;
    const int wib  = threadIdx.x >> 6;
    const int n    = blockIdx.x * 4 + wib;
    if (n >= N) return;

    const int g   = lane >> 4;     // edge slot 0..3
    const int l16 = lane & 15;
    const int d0  = l16 * 8;       // 8 dims per lane (within one head)

    float c1[8], c2[8], vd[8];
    {
        float4 a0 = *(const float4*)(attn + d0);
        float4 a1 = *(const float4*)(attn + d0 + 4);
        c1[0] = 0.6f * a0.x; c2[0] = 0.4f * a0.x;
        c1[1] = 0.6f * a0.y; c2[1] = 0.4f * a0.y;
        c1[2] = 0.6f * a0.z; c2[2] = 0.4f * a0.z;
        c1[3] = 0.6f * a0.w; c2[3] = 0.4f * a0.w;
        c1[4] = 0.6f * a1.x; c2[4] = 0.4f * a1.x;
        c1[5] = 0.6f * a1.y; c2[5] = 0.4f * a1.y;
        c1[6] = 0.6f * a1.z; c2[6] = 0.4f * a1.z;
        c1[7] = 0.6f * a1.w; c2[7] = 0.4f * a1.w;
        uint4 vdu = *(const uint4*)(fdB + (size_t)n * 128 + d0);
        vd[0] = __uint_as_float(vdu.x << 16);
        vd[1] = __uint_as_float(vdu.x & 0xffff0000u);
        vd[2] = __uint_as_float(vdu.y << 16);
        vd[3] = __uint_as_float(vdu.y & 0xffff0000u);
        vd[4] = __uint_as_float(vdu.z << 16);
        vd[5] = __uint_as_float(vdu.z & 0xffff0000u);
        vd[6] = __uint_as_float(vdu.w << 16);
        vd[7] = __uint_as_float(vdu.w & 0xffff0000u);
    }

    const int lo = rs[n], hi = rs[n + 1];
    const int T  = (hi - lo + 3) >> 2;

    float den = 0.f;
    float w[8];
    #pragma unroll
    for (int j = 0; j < 8; ++j) w[j] = 0.f;

    int i = lo + g;
    bool vA = (i < hi);
    int sA = vA ? srcSorted[i] : 0;
    uint4 rA = *(const uint4*)(fs + (size_t)sA * 128 + d0);

    for (int t = 0; t < T; ++t) {
        const int inx = i + 4;
        const bool vB = (inx < hi);
        const int sB = vB ? srcSorted[inx] : 0;
        uint4 rB = *(const uint4*)(fs + (size_t)sB * 128 + d0);   // prefetch

        float v[8];
        v[0] = __uint_as_float(rA.x << 16);
        v[1] = __uint_as_float(rA.x & 0xffff0000u);
        v[2] = __uint_as_float(rA.y << 16);
        v[3] = __uint_as_float(rA.y & 0xffff0000u);
        v[4] = __uint_as_float(rA.z << 16);
        v[5] = __uint_as_float(rA.z & 0xffff0000u);
        v[6] = __uint_as_float(rA.w << 16);
        v[7] = __uint_as_float(rA.w & 0xffff0000u);

        float p = 0.f;
        #pragma unroll
        for (int j = 0; j < 8; ++j) {
            float e = v[j] + vd[j];
            p = fmaf(c1[j], e, p);
            p = fmaf(c2[j], fabsf(e), p);
        }
        p += __shfl_xor(p, 1);
        p += __shfl_xor(p, 2);            // head score (4 lanes per head)
        float exv = vA ? __expf(p) : 0.f;
        den += exv;
        #pragma unroll
        for (int j = 0; j < 8; ++j) w[j] = fmaf(exv, v[j], w[j]);

        vA = vB; rA = rB; i = inx;
    }

    den += __shfl_xor(den, 16);
    den += __shfl_xor(den, 32);
    #pragma unroll
    for (int j = 0; j < 8; ++j) {
        w[j] += __shfl_xor(w[j], 16);
        w[j] += __shfl_xor(w[j], 32);
    }

    if (g == 0) {
        const float inv = den > 0.f ? 1.0f / den : 0.f;
        const int gg = gid[n];
        float4 x0 = *(const float4*)(x  + (size_t)n * 128 + d0);
        float4 x1 = *(const float4*)(x  + (size_t)n * 128 + d0 + 4);
        float4 t0 = *(const float4*)(tc + (size_t)gg * 128 + d0);
        float4 t1 = *(const float4*)(tc + (size_t)gg * 128 + d0 + 4);
        float4 g0 = *(const float4*)(gat_bias + d0);
        float4 g1 = *(const float4*)(gat_bias + d0 + 4);
        float o[8];
        o[0] = gelu_erf(w[0] * inv + g0.x) + t0.x + x0.x;
        o[1] = gelu_erf(w[1] * inv + g0.y) + t0.y + x0.y;
        o[2] = gelu_erf(w[2] * inv + g0.z) + t0.z + x0.z;
        o[3] = gelu_erf(w[3] * inv + g0.w) + t0.w + x0.w;
        o[4] = gelu_erf(w[4] * inv + g1.x) + t1.x + x1.x;
        o[5] = gelu_erf(w[5] * inv + g1.y) + t1.y + x1.y;
        o[6] = gelu_erf(w[6] * inv + g1.z) + t1.z + x1.z;
        o[7] = gelu_erf(w[7] * inv + g1.w) + t1.w + x1.w;
        uint4 pk;
        pk.x = (unsigned int)f2bf(o[0]) | ((unsigned int)f2bf(o[1]) << 16);
        pk.y = (unsigned int)f2bf(o[2]) | ((unsigned int)f2bf(o[3]) << 16);
        pk.z = (unsigned int)f2bf(o[4]) | ((unsigned int)f2bf(o[5]) << 16);
        pk.w = (unsigned int)f2bf(o[6]) | ((unsigned int)f2bf(o[7]) << 16);
        *(uint4*)(hm + (size_t)n * 128 + d0) = pk;
    }
}

// ---------------------------------------------------------------------------
// LN2 + FFN via MFMA. 16 rows/block, 4 waves. hmid input is BF16 [N][128].
// ---------------------------------------------------------------------------
__global__ __launch_bounds__(256) void combine_ffn(
    const unsigned short* __restrict__ hmg,
    const float* __restrict__ ln_g, const float* __restrict__ ln_b,
    const unsigned short* __restrict__ pW1, const float* __restrict__ b1,
    const unsigned short* __restrict__ pW2, const float* __restrict__ b2,
    float* __restrict__ out, int nrows)
{
    __shared__ __align__(16) float hs[RB][132];
    __shared__ __align__(16) unsigned short pa[4 * 64 * 8];
    __shared__ __align__(16) unsigned short a2[RB * 264];
    __shared__ float s_mu[RB], s_rs[RB];

    const int tid  = threadIdx.x;
    const int row0 = blockIdx.x * RB;
    const int lane = tid & 63;
    const int w    = tid >> 6;

    {
        int row = tid >> 4;
        int c0  = (tid & 15) * 8;
        uint4 u = make_uint4(0, 0, 0, 0);
        if (row0 + row < nrows) u = *(const uint4*)(hmg + (size_t)(row0 + row) * 128 + c0);
        float* hr = &hs[row][c0];
        hr[0] = __uint_as_float(u.x << 16);
        hr[1] = __uint_as_float(u.x & 0xffff0000u);
        hr[2] = __uint_as_float(u.y << 16);
        hr[3] = __uint_as_float(u.y & 0xffff0000u);
        hr[4] = __uint_as_float(u.z << 16);
        hr[5] = __uint_as_float(u.z & 0xffff0000u);
        hr[6] = __uint_as_float(u.w << 16);
        hr[7] = __uint_as_float(u.w & 0xffff0000u);
    }
    __syncthreads();

    {
        const int ln = lane;
        #pragma unroll
        for (int rr = 0; rr < 4; ++rr) {
            int row = w * 4 + rr;
            float v0 = hs[row][ln * 2], v1 = hs[row][ln * 2 + 1];
            float s = v0 + v1, sq = v0 * v0 + v1 * v1;
            #pragma unroll
            for (int m = 32; m; m >>= 1) { s += __shfl_xor(s, m); sq += __shfl_xor(sq, m); }
            if (ln == 0) {
                float mu  = s * (1.0f / 128.0f);
                float var = sq * (1.0f / 128.0f) - mu * mu;
                s_mu[row] = mu;
                s_rs[row] = rsqrtf(var + LN_EPS);
            }
        }
    }
    __syncthreads();

    {
        const int kt  = w;
        const int row = lane & 15;
        const int k0  = kt * 32 + 8 * (lane >> 4);
        float mu = s_mu[row], rs2 = s_rs[row];
        float4 u  = *(float4*)&hs[row][k0];
        float4 v  = *(float4*)&hs[row][k0 + 4];
        float4 g0 = *(const float4*)&ln_g[k0];
        float4 g1 = *(const float4*)&ln_g[k0 + 4];
        float4 c0 = *(const float4*)&ln_b[k0];
        float4 c1 = *(const float4*)&ln_b[k0 + 4];
        short8v pv;
        pv[0] = (short)f2bf((u.x - mu) * rs2 * g0.x + c0.x);
        pv[1] = (short)f2bf((u.y - mu) * rs2 * g0.y + c0.y);
        pv[2] = (short)f2bf((u.z - mu) * rs2 * g0.z + c0.z);
        pv[3] = (short)f2bf((u.w - mu) * rs2 * g0.w + c0.w);
        pv[4] = (short)f2bf((v.x - mu) * rs2 * g1.x + c1.x);
        pv[5] = (short)f2bf((v.y - mu) * rs2 * g1.y + c1.y);
        pv[6] = (short)f2bf((v.z - mu) * rs2 * g1.z + c1.z);
        pv[7] = (short)f2bf((v.w - mu) * rs2 * g1.w + c1.w);
        *(short8v*)&pa[(kt * 64 + lane) * 8] = pv;
    }
    __syncthreads();

    {
        short8v a[4];
        #pragma unroll
        for (int kt = 0; kt < 4; ++kt)
            a[kt] = *(const short8v*)&pa[(kt * 64 + lane) * 8];

        #pragma unroll
        for (int jj = 0; jj < 4; ++jj) {
            const int nt = 4 * w + jj;
            floatx4 acc = {0.f, 0.f, 0.f, 0.f};
            #pragma unroll
            for (int kt = 0; kt < 4; ++kt) {
                short8v b = *(const short8v*)(pW1 + (size_t)((nt * 4 + kt) * 64 + lane) * 8);
                acc = __builtin_amdgcn_mfma_f32_16x16x32_bf16(a[kt], b, acc, 0, 0, 0);
            }
            const int col = nt * 16 + (lane & 15);
            const float bb = b1[col];
            #pragma unroll
            for (int r = 0; r < 4; ++r) {
                int rowD = 4 * (lane >> 4) + r;
                a2[rowD * 264 + col] = f2bf(gelu_erf(acc[r] + bb));
            }
        }
    }
    __syncthreads();

    {
        floatx4 acc2[2] = {{0.f, 0.f, 0.f, 0.f}, {0.f, 0.f, 0.f, 0.f}};
        #pragma unroll
        for (int kt = 0; kt < 8; ++kt) {
            short8v af = *(const short8v*)&a2[(lane & 15) * 264 + kt * 32 + 8 * (lane >> 4)];
            #pragma unroll
            for (int j = 0; j < 2; ++j) {
                const int nt = 2 * w + j;
                short8v b = *(const short8v*)(pW2 + (size_t)((nt * 8 + kt) * 64 + lane) * 8);
                acc2[j] = __builtin_amdgcn_mfma_f32_16x16x32_bf16(af, b, acc2[j], 0, 0, 0);
            }
        }
        #pragma unroll
        for (int j = 0; j < 2; ++j) {
            const int col = (2 * w + j) * 16 + (lane & 15);
            const float bb = b2[col];
            #pragma unroll
            for (int r = 0; r < 4; ++r) {
                int rowD = 4 * (lane >> 4) + r;
                int grow = row0 + rowD;
                if (grow < nrows)
                    out[(size_t)grow * 128 + col] = hs[rowD][col] + acc2[j][r] + bb;
            }
        }
    }
}

// ---------------------------------------------------------------------------
extern "C" void kernel_launch(void* const* d_in, const int* in_sizes, int n_in,
                              void* d_out, int out_size, void* d_ws, size_t ws_size,
                              hipStream_t stream)
{
    const float* x    = (const float*)d_in[0];
    const int*   src  = (const int*)  d_in[1];
    const int*   dst  = (const int*)  d_in[2];
    const int*   gid  = (const int*)  d_in[3];
    const float* temb = (const float*)d_in[4];
    const float* Wsrc = (const float*)d_in[5];
    const float* bsrc = (const float*)d_in[6];
    const float* Wdst = (const float*)d_in[7];
    const float* bdst = (const float*)d_in[8];
    const float* attn = (const float*)d_in[9];
    const float* gbias= (const float*)d_in[10];
    const float* ln1g = (const float*)d_in[11];
    const float* ln1b = (const float*)d_in[12];
    const float* ln2g = (const float*)d_in[13];
    const float* ln2b = (const float*)d_in[14];
    const float* tW   = (const float*)d_in[15];
    const float* tb   = (const float*)d_in[16];
    const float* W1   = (const float*)d_in[17];
    const float* b1   = (const float*)d_in[18];
    const float* W2   = (const float*)d_in[19];
    const float* b2   = (const float*)d_in[20];

    const int N = in_sizes[0] / 128;
    const int E = in_sizes[1];
    const int B = in_sizes[4] / 128;
    float* out = (float*)d_out;

    char* ws = (char*)d_ws;
    size_t off = 0;
    auto alloc = [&](size_t bytes) { void* p = ws + off; off += (bytes + 255) & ~(size_t)255; return p; };
    unsigned short* fs  = (unsigned short*)alloc((size_t)N * 128 * 2);  // bf16 feat_src [N][128]
    unsigned short* fdB = (unsigned short*)alloc((size_t)N * 128 * 2);  // bf16 feat_dst [N][128]
    unsigned short* hm  = (unsigned short*)alloc((size_t)N * 128 * 2);  // bf16 hmid [N][128]
    int*   deg          = (int*)           alloc((size_t)N * 4);
    int*   rsb          = (int*)           alloc((size_t)(N + 1) * 4);
    int*   rank         = (int*)           alloc((size_t)E * 4);
    int*   srcSorted    = (int*)           alloc((size_t)E * 4);
    float* tc           = (float*)         alloc((size_t)B * 128 * 4);
    int*   btot         = (int*)           alloc((size_t)1024 * 4);
    unsigned short* pWs = (unsigned short*)alloc((size_t)128 * 128 * 2);
    unsigned short* pWd = (unsigned short*)alloc((size_t)128 * 128 * 2);
    unsigned short* pW1 = (unsigned short*)alloc((size_t)128 * 256 * 2);
    unsigned short* pW2 = (unsigned short*)alloc((size_t)256 * 128 * 2);

    const int nbScan = (N + 1023) >> 10;     // 98 (<=128 required by scan_tops)
    const int nRank  = (E + 255) / 256;      // 6250
    const int nLn1   = (N + RB - 1) / RB;    // 6250
    const int nFill  = (E + 255) / 256;      // 6250

    hipMemsetAsync(deg, 0, (size_t)N * 4, stream);
    prep<<<nRank + 49, 256, 0, stream>>>(dst, deg, rank, E, nRank,
        temb, tW, tb, tc, B, Wsrc, pWs, Wdst, pWd, W1, pW1, W2, pW2);
    scan_blocks<<<nbScan, 256, 0, stream>>>(deg, rsb, btot, N);
    scan_tops<<<1, 64, 0, stream>>>(btot, nbScan, rsb, N, E);
    scan_add<<<(N + 255) / 256, 256, 0, stream>>>(rsb, btot, N);
    ln1_fill<<<nLn1 + nFill, 256, 0, stream>>>(
        x, ln1g, ln1b, pWs, bsrc, pWd, bdst, fs, fdB, N, nLn1,
        dst, src, rsb, rank, srcSorted, E);
    gat_gather<<<(N + 3) / 4, 256, 0, stream>>>(
        fs, fdB, hm, x, srcSorted, rsb, attn, gbias, gid, tc, N);
    combine_ffn<<<(N + RB - 1) / RB, 256, 0, stream>>>(
        hm, ln2g, ln2b, pW1, b1, pW2, b2, out, N);
}